// Round 8
// baseline (292.375 us; speedup 1.0000x reference)
//
#include <hip/hip_runtime.h>
#include <hip/hip_fp16.h>

#define H 64
#define BSH 8            // 256 nodes per bucket
#define BNODES 256
#define NBMAX 256
#define TILE 2048
#define EPT 8            // edges per thread in k_part
#define BCAP 9216        // capacity per bucket (mean 8163, sd ~90)

// ---------- pass A: partition edges into 256-node dst-buckets ----------
// entry = src (16b) | type<<16 (3b) | (dst&255)<<19 (8b)
__global__ __launch_bounds__(256) void k_part(const int* __restrict__ gsrc,
                                              const int* __restrict__ gdst,
                                              const int* __restrict__ type,
                                              int* __restrict__ bcur,
                                              int* __restrict__ barr,
                                              int E, int nb) {
    __shared__ int hist[NBMAX];
    __shared__ int pfx[NBMAX];
    __shared__ int gpos[NBMAX];
    __shared__ int cursor[NBMAX];
    __shared__ int stage[TILE];
    __shared__ unsigned char bof[TILE];
    int t = threadIdx.x;
    int base = blockIdx.x * TILE;
    for (int i = t; i < nb; i += 256) hist[i] = 0;
    __syncthreads();
    int myb[EPT]; int mypk[EPT];
    #pragma unroll
    for (int k = 0; k < EPT; ++k) {
        int j = base + k * 256 + t;             // coalesced
        if (j < E) {
            int d = gdst[j];
            int s = gsrc[j];
            int ty = type[s];                   // scattered 4B (L2-resident)
            int b = d >> BSH;
            myb[k] = b;
            mypk[k] = s | (ty << 16) | ((d & (BNODES - 1)) << 19);
            atomicAdd(&hist[b], 1);
        } else myb[k] = -1;
    }
    __syncthreads();
    if (t == 0) { int run = 0; for (int b = 0; b < nb; ++b) { pfx[b] = run; run += hist[b]; } }
    __syncthreads();
    if (t < nb) {
        cursor[t] = pfx[t];
        gpos[t] = hist[t] ? atomicAdd(&bcur[t], hist[t]) : 0;
    }
    __syncthreads();
    #pragma unroll
    for (int k = 0; k < EPT; ++k) if (myb[k] >= 0) {
        int p = atomicAdd(&cursor[myb[k]], 1);
        stage[p] = mypk[k];
        bof[p] = (unsigned char)myb[k];
    }
    __syncthreads();
    int total = pfx[nb - 1] + hist[nb - 1];
    for (int i = t; i < total; i += 256) {       // coalesced segment write-out
        int b = bof[i];
        barr[(size_t)b * BCAP + gpos[b] + (i - pfx[b])] = stage[i];
    }
}

// ---------- pass B: per-bucket counting sort + layer-1 (algebraic) fused ----------
// emits cnt/off/csr AND x1h = relu(b1 + EW[tv] + sum_t (thist_t/c) EW[t]) as fp16
__global__ __launch_bounds__(256) void k_bsort(const int* __restrict__ bcnt,
                                               const int* __restrict__ barr,
                                               const int* __restrict__ type,
                                               const float* __restrict__ embed,
                                               const float* __restrict__ W1,
                                               const float* __restrict__ b1,
                                               int* __restrict__ csr,
                                               int* __restrict__ cnt,
                                               int* __restrict__ off,
                                               __half* __restrict__ x1h,
                                               int N, int nb) {
    __shared__ float W1s[H * H];        // 16KB
    __shared__ float es[8 * H];         // 2KB
    __shared__ float ews[8 * H];        // 2KB  EW = embed @ W1
    __shared__ float bs1[H];
    __shared__ int hist[BNODES];
    __shared__ int loff[BNODES];
    __shared__ int thist[BNODES * 8];   // 8KB per-node x type
    __shared__ int cbase_s;
    int b = blockIdx.x;
    int t = threadIdx.x;
    int n0 = b << BSH;
    int nn = min(BNODES, N - n0);
    int cE = bcnt[b];
    const int* arr = barr + (size_t)b * BCAP;
    for (int i = t; i < H * H; i += 256) W1s[i] = W1[i];
    for (int i = t; i < 8 * H; i += 256) es[i] = embed[i];
    if (t < H) bs1[t] = b1[t];
    hist[t] = 0;
    for (int i = t; i < BNODES * 8; i += 256) thist[i] = 0;
    if (t == 0) { int run = 0; for (int x = 0; x < b; ++x) run += bcnt[x]; cbase_s = run; }
    __syncthreads();
    // EW = e @ W1 (512 outputs, 2 per thread)
    {
        float a1 = 0.f, a2 = 0.f;
        int o1 = t, o2 = t + 256;
        int ty1 = o1 >> 6, n1 = o1 & 63, ty2 = o2 >> 6, n2 = o2 & 63;
        for (int k = 0; k < H; ++k) {
            a1 = fmaf(es[ty1 * H + k], W1s[k * H + n1], a1);
            a2 = fmaf(es[ty2 * H + k], W1s[k * H + n2], a2);
        }
        ews[o1] = a1; ews[o2] = a2;
    }
    // histogram over this bucket's edges (node + node-x-type)
    for (int i = t; i < cE; i += 256) {
        int e = arr[i];
        int loc = (e >> 19) & (BNODES - 1);
        atomicAdd(&hist[loc], 1);
        atomicAdd(&thist[loc * 8 + ((e >> 16) & 7)], 1);
    }
    __syncthreads();
    if (t == 0) { int run = 0; for (int i = 0; i < BNODES; ++i) { loff[i] = run; run += hist[i]; } }
    __syncthreads();
    int cbase = cbase_s;
    for (int i = t; i < nn; i += 256) {
        cnt[n0 + i] = hist[i];
        off[n0 + i] = cbase + loff[i];
    }
    __syncthreads();
    for (int i = t; i < cE; i += 256) {
        int e = arr[i];
        int p = atomicAdd(&loff[(e >> 19) & (BNODES - 1)], 1);
        csr[cbase + p] = e & 0x7FFFF;            // src | type<<16
    }
    __syncthreads();
    // layer-1 output: wave per node round-robin
    int lane = t & 63, w = t >> 6;
    for (int v = w; v < nn; v += 4) {
        int c = hist[v];
        float invc = (c > 0) ? 1.f / (float)c : 0.f;
        int tv = type[n0 + v];
        float z = bs1[lane] + ews[tv * H + lane];
        #pragma unroll
        for (int ty = 0; ty < 8; ++ty)
            z = fmaf((float)thist[v * 8 + ty] * invc, ews[ty * H + lane], z);
        x1h[(size_t)(n0 + v) * H + lane] = __float2half_rn(fmaxf(z, 0.f));
    }
}

__device__ __forceinline__ float2 h2f2(unsigned u) {
    __half2 h = *reinterpret_cast<__half2*>(&u);
    return __half22float2(h);
}

// ---------- layer 2: chunk-16 gather (8 rows x 2 j-steps), VGPR<=64 for 8 waves/SIMD ----------
__global__ __launch_bounds__(256, 8) void k_l2(const __half* __restrict__ x1h,
                                               float* __restrict__ x2,
                                               const int* __restrict__ off,
                                               const int* __restrict__ cnt,
                                               const int* __restrict__ csr,
                                               const float* __restrict__ W,
                                               const float* __restrict__ b, int n) {
    __shared__ float Ws[H * H];
    __shared__ float bs[H];
    for (int i = threadIdx.x; i < H * H; i += 256) Ws[i] = W[i];
    if (threadIdx.x < H) bs[threadIdx.x] = b[threadIdx.x];
    __syncthreads();
    int lane = threadIdx.x & 63;
    int oct = lane >> 3;         // which of 8 rows per j-step
    int sl = lane & 7;           // dim group: dims 8*sl..8*sl+7
    int wid = (blockIdx.x * blockDim.x + threadIdx.x) >> 6;
    int nw = (gridDim.x * blockDim.x) >> 6;
    const uint4* xh4 = (const uint4*)x1h;   // row = 8 x uint4 (64 halves)
    for (int v = wid; v < n; v += nw) {
        int lo = off[v];
        int c = cnt[v];
        float acc[8] = {0.f, 0.f, 0.f, 0.f, 0.f, 0.f, 0.f, 0.f};
        for (int i = 0; i < c; i += 16) {
            int idx = csr[lo + min(i + (lane & 15), c - 1)];   // coalesced
            #pragma unroll
            for (int j = 0; j < 2; ++j) {
                int r = i + j * 8 + oct;
                int s = __shfl(idx, j * 8 + oct, 64) & 0xffff;
                uint4 u = xh4[(size_t)s * 8 + sl];
                float m = (r < c) ? 1.f : 0.f;
                float2 f0 = h2f2(u.x), f1 = h2f2(u.y), f2 = h2f2(u.z), f3 = h2f2(u.w);
                acc[0] = fmaf(m, f0.x, acc[0]);
                acc[1] = fmaf(m, f0.y, acc[1]);
                acc[2] = fmaf(m, f1.x, acc[2]);
                acc[3] = fmaf(m, f1.y, acc[3]);
                acc[4] = fmaf(m, f2.x, acc[4]);
                acc[5] = fmaf(m, f2.y, acc[5]);
                acc[6] = fmaf(m, f3.x, acc[6]);
                acc[7] = fmaf(m, f3.y, acc[7]);
            }
        }
        #pragma unroll
        for (int d = 8; d < 64; d <<= 1) {
            #pragma unroll
            for (int k = 0; k < 8; ++k) acc[k] += __shfl_xor(acc[k], d, 64);
        }
        // self row loaded AFTER gather loop (short liveness)
        uint4 us = xh4[(size_t)v * 8 + sl];
        float inv = (c > 0) ? 1.f / (float)c : 0.f;
        float2 s0 = h2f2(us.x), s1 = h2f2(us.y), s2 = h2f2(us.z), s3 = h2f2(us.w);
        acc[0] = s0.x + acc[0] * inv;  acc[1] = s0.y + acc[1] * inv;
        acc[2] = s1.x + acc[2] * inv;  acc[3] = s1.y + acc[3] * inv;
        acc[4] = s2.x + acc[4] * inv;  acc[5] = s2.y + acc[5] * inv;
        acc[6] = s3.x + acc[6] * inv;  acc[7] = s3.y + acc[7] * inv;
        // matvec with dual accumulators (break serial fma chain)
        float o0 = bs[lane], o1 = 0.f;
        #pragma unroll
        for (int k = 0; k < H; k += 2) {
            float hk0 = __shfl(acc[k & 7], k >> 3, 64);
            float hk1 = __shfl(acc[(k + 1) & 7], (k + 1) >> 3, 64);
            o0 = fmaf(hk0, Ws[k * H + lane], o0);
            o1 = fmaf(hk1, Ws[(k + 1) * H + lane], o1);
        }
        x2[(size_t)v * H + lane] = fmaxf(o0 + o1, 0.f);
    }
}

// ---------- precompute A = x @ We1_top + be1, B = x @ We1_bot (fp16 out) ----------
__global__ __launch_bounds__(256) void k_pre(const float* __restrict__ x,
                                             __half* __restrict__ A,
                                             __half* __restrict__ B,
                                             const float* __restrict__ We1,
                                             const float* __restrict__ be1, int n) {
    __shared__ float Ws[2 * H * H];
    __shared__ float bs[H];
    for (int i = threadIdx.x; i < 2 * H * H; i += 256) Ws[i] = We1[i];
    if (threadIdx.x < H) bs[threadIdx.x] = be1[threadIdx.x];
    __syncthreads();
    int lane = threadIdx.x & 63;
    int wid = (blockIdx.x * blockDim.x + threadIdx.x) >> 6;
    int nw = (gridDim.x * blockDim.x) >> 6;
    for (int v = wid; v < n; v += nw) {
        float xv = x[(size_t)v * H + lane];
        float a = bs[lane];
        float bb = 0.f;
        #pragma unroll
        for (int k = 0; k < H; ++k) {
            float xk = __shfl(xv, k, 64);
            a = fmaf(xk, Ws[k * H + lane], a);
            bb = fmaf(xk, Ws[(H + k) * H + lane], bb);
        }
        A[(size_t)v * H + lane] = __float2half_rn(a);
        B[(size_t)v * H + lane] = __float2half_rn(bb);
    }
}

// ---------- query edge scoring: one-shot, 8 edges/wave, 8 lanes/edge ----------
__global__ __launch_bounds__(256) void k_edge(const __half* __restrict__ A,
                                              const __half* __restrict__ B,
                                              const int* __restrict__ qs,
                                              const int* __restrict__ qd,
                                              const float* __restrict__ We2,
                                              const float* __restrict__ be2,
                                              float* __restrict__ out, int q) {
    const uint4* A4 = (const uint4*)A;
    const uint4* B4 = (const uint4*)B;
    int lane = threadIdx.x & 63;
    int sub  = lane >> 3;
    int sl   = lane & 7;
    int wid = (blockIdx.x * blockDim.x + threadIdx.x) >> 6;
    const float4* W24 = (const float4*)We2;
    float4 wlo = W24[sl * 2];
    float4 whi = W24[sl * 2 + 1];
    float b2 = be2[0];
    int e = wid * 8 + sub;
    if (e < q) {
        int u = qs[e], v = qd[e];
        uint4 ra = A4[(size_t)u * 8 + sl];
        uint4 rb = B4[(size_t)v * 8 + sl];
        float2 a0 = h2f2(ra.x), a1 = h2f2(ra.y), a2 = h2f2(ra.z), a3 = h2f2(ra.w);
        float2 b0 = h2f2(rb.x), b1 = h2f2(rb.y), b2v = h2f2(rb.z), b3 = h2f2(rb.w);
        float p = fmaxf(a0.x + b0.x, 0.f) * wlo.x
                + fmaxf(a0.y + b0.y, 0.f) * wlo.y
                + fmaxf(a1.x + b1.x, 0.f) * wlo.z
                + fmaxf(a1.y + b1.y, 0.f) * wlo.w
                + fmaxf(a2.x + b2v.x, 0.f) * whi.x
                + fmaxf(a2.y + b2v.y, 0.f) * whi.y
                + fmaxf(a3.x + b3.x, 0.f) * whi.z
                + fmaxf(a3.y + b3.y, 0.f) * whi.w;
        p += __shfl_xor(p, 1, 64);
        p += __shfl_xor(p, 2, 64);
        p += __shfl_xor(p, 4, 64);
        if (sl == 0) out[e] = p + b2;
    }
}

extern "C" void kernel_launch(void* const* d_in, const int* in_sizes, int n_in,
                              void* d_out, int out_size, void* d_ws, size_t ws_size,
                              hipStream_t stream) {
    const int* node_type = (const int*)d_in[0];
    const int* gsrc      = (const int*)d_in[1];
    const int* gdst      = (const int*)d_in[2];
    const int* qsrc      = (const int*)d_in[3];
    const int* qdst      = (const int*)d_in[4];
    const float* embed   = (const float*)d_in[5];
    const float* W1      = (const float*)d_in[6];
    const float* b1      = (const float*)d_in[7];
    const float* W2      = (const float*)d_in[8];
    const float* b2      = (const float*)d_in[9];
    const float* We1     = (const float*)d_in[10];
    const float* be1     = (const float*)d_in[11];
    const float* We2     = (const float*)d_in[12];
    const float* be2     = (const float*)d_in[13];
    float* out = (float*)d_out;

    const int N = in_sizes[0];
    const int E = in_sizes[1];
    const int Q = in_sizes[3];
    const int nb = (N + BNODES - 1) >> BSH;    // 196 buckets

    // workspace layout (256B aligned)
    char* ws = (char*)d_ws;
    size_t o = 0;
    auto alloc = [&](size_t bytes) { void* p = ws + o; o = (o + bytes + 255) & ~(size_t)255; return p; };
    float* x2  = (float*)alloc((size_t)N * H * sizeof(float));
    __half* x1h = (__half*)alloc((size_t)N * H * sizeof(__half));
    __half* Ah  = (__half*)alloc((size_t)N * H * sizeof(__half));
    __half* Bh  = (__half*)alloc((size_t)N * H * sizeof(__half));
    int* cnt  = (int*)alloc((size_t)N * sizeof(int));
    int* off  = (int*)alloc((size_t)N * sizeof(int));
    int* csr  = (int*)alloc((size_t)E * sizeof(int));
    int* barr = (int*)alloc((size_t)nb * BCAP * sizeof(int));
    int* bcur = (int*)alloc((size_t)NBMAX * sizeof(int));
    (void)ws_size;

    // bucketed CSR build + fused layer 1
    hipMemsetAsync(bcur, 0, (size_t)NBMAX * sizeof(int), stream);
    k_part<<<(E + TILE - 1) / TILE, 256, 0, stream>>>(gsrc, gdst, node_type, bcur, barr, E, nb);
    k_bsort<<<nb, 256, 0, stream>>>(bcur, barr, node_type, embed, W1, b1,
                                    csr, cnt, off, x1h, N, nb);

    // layer 2: fp16 gathers, chunk-16, 8 waves/SIMD
    k_l2<<<4096, 256, 0, stream>>>(x1h, x2, off, cnt, csr, W2, b2, N);

    // edge MLP
    k_pre<<<2048, 256, 0, stream>>>(x2, Ah, Bh, We1, be1, N);
    int eblocks = (Q + 31) / 32;   // 4 waves/block x 8 edges/wave
    k_edge<<<eblocks, 256, 0, stream>>>(Ah, Bh, qsrc, qdst, We2, be2, out, Q);
}